// Round 6
// baseline (329.440 us; speedup 1.0000x reference)
//
#include <hip/hip_runtime.h>
#include <hip/hip_bf16.h>

typedef unsigned short u16;
typedef unsigned int u32;
typedef __bf16 bf16x8 __attribute__((ext_vector_type(8)));
typedef float f32x4 __attribute__((ext_vector_type(4)));
typedef float f32x16 __attribute__((ext_vector_type(16)));
typedef u16 u16x4 __attribute__((ext_vector_type(4)));
typedef u16 u16x8 __attribute__((ext_vector_type(8)));

#define D_IN 4096
#define D_OUT 4096
#define M_TOT 8192
#define RANK_ 16

#define BM 256
#define BN 256
#define BK 64
#define NT (D_IN / BK)   // 64 K-tiles
#define OPB 2            // dequant rows per block

__device__ __forceinline__ u16 f2bf(float f) {
    union { float f; u32 u; } v; v.f = f;
    u32 u = v.u;
    u32 r = (u + 0x7FFFu + ((u >> 16) & 1u)) >> 16;  // round-to-nearest-even
    return (u16)r;
}

// W_eff[o,i] = q[o,i]*scale[o] + min[o] + 2*sum_r B[o,r]*A[r,i]  -> bf16
__global__ __launch_bounds__(256) void dequant_fold_kernel(
        const int* __restrict__ q, const float* __restrict__ wmin,
        const float* __restrict__ wscale, const float* __restrict__ A,
        const float* __restrict__ Bm, u16* __restrict__ Wb) {
    const int K = D_IN;
    int o0 = blockIdx.x * OPB;
    float s0 = wscale[o0], s1 = wscale[o0 + 1];
    float m0 = wmin[o0],   m1 = wmin[o0 + 1];
    float Br0[RANK_], Br1[RANK_];   // block-uniform -> SGPRs
    #pragma unroll
    for (int r = 0; r < RANK_; ++r) {
        Br0[r] = 2.0f * Bm[(size_t)o0 * RANK_ + r];
        Br1[r] = 2.0f * Bm[(size_t)(o0 + 1) * RANK_ + r];
    }
    for (int i4 = threadIdx.x; i4 < K / 4; i4 += 256) {
        int i = i4 * 4;
        int4 q0 = *(const int4*)(q + (size_t)o0 * K + i);
        int4 q1 = *(const int4*)(q + (size_t)(o0 + 1) * K + i);
        float v00 = (float)q0.x * s0 + m0, v01 = (float)q0.y * s0 + m0;
        float v02 = (float)q0.z * s0 + m0, v03 = (float)q0.w * s0 + m0;
        float v10 = (float)q1.x * s1 + m1, v11 = (float)q1.y * s1 + m1;
        float v12 = (float)q1.z * s1 + m1, v13 = (float)q1.w * s1 + m1;
        #pragma unroll
        for (int r = 0; r < RANK_; ++r) {
            float4 av = *(const float4*)(A + (size_t)r * K + i);
            v00 += Br0[r] * av.x; v01 += Br0[r] * av.y;
            v02 += Br0[r] * av.z; v03 += Br0[r] * av.w;
            v10 += Br1[r] * av.x; v11 += Br1[r] * av.y;
            v12 += Br1[r] * av.z; v13 += Br1[r] * av.w;
        }
        u16x4 o0v, o1v;
        o0v.x = f2bf(v00); o0v.y = f2bf(v01); o0v.z = f2bf(v02); o0v.w = f2bf(v03);
        o1v.x = f2bf(v10); o1v.y = f2bf(v11); o1v.z = f2bf(v12); o1v.w = f2bf(v13);
        *(u16x4*)(Wb + (size_t)o0 * K + i) = o0v;
        *(u16x4*)(Wb + (size_t)(o0 + 1) * K + i) = o1v;
    }
}

// fp32 -> bf16, 8 elems/thread
__global__ void xcast_kernel(const float* __restrict__ x, u16* __restrict__ xb) {
    size_t i = (size_t)blockIdx.x * blockDim.x + threadIdx.x;
    const float4* p = (const float4*)x + i * 2;
    float4 a = p[0];
    float4 b = p[1];
    u16x8 o;
    o[0] = f2bf(a.x); o[1] = f2bf(a.y); o[2] = f2bf(a.z); o[3] = f2bf(a.w);
    o[4] = f2bf(b.x); o[5] = f2bf(b.y); o[6] = f2bf(b.z); o[7] = f2bf(b.w);
    *(u16x8*)(xb + i * 8) = o;
}

// ---- 256x256 8-phase GEMM on v_mfma_f32_32x32x16_bf16 ----
// Per wave (128x64): 4 M-blocks x 2 N-blocks of 32x32; K-tile 64 = 4 ksteps.
// Phases: P1(mf01,nf0) P2(mf01,nf1) P3(mf23,nf0) P4(mf23,nf1); 8 MFMA each.
// nf0 frags last used P3 -> P4 preloads NEXT tile's nf0 into same regs
// (no wait: vmcnt(8)+barrier at P4 guarantees tile tt+1 landed).
// Reads/phase: 8/4/8/4.  Staging (race-free, proven): P2: A-mf01 + B-nf0,
// P3: B-nf1, P4: A-mf23 (readers drained at a prior lgkm(0)+bar).
// vmcnt(8) once per tile = 8 newest (tile tt+2) stay in flight.
// A-frag (m74/m101): lane holds row=l&31, k=(l>>5)*8+[0,8); C/D: col=l&31,
// row=(reg&3)+8*(reg>>2)+4*(l>>5).

#define STAGE_R(sarr, larr, base, kt) do { _Pragma("unroll") \
    for (int j_ = 0; j_ < 2; ++j_) \
        __builtin_amdgcn_global_load_lds( \
            (__attribute__((address_space(1))) u32*)(sarr[j_] + (kt) * 64), \
            (__attribute__((address_space(3))) u32*)(smem + (base) + larr[j_]), \
            16, 0, 0); } while (0)

#define MFMA32(d, va, vb) d = __builtin_amdgcn_mfma_f32_32x32x16_bf16(va, vb, d, 0, 0, 0)

__global__ __launch_bounds__(512, 2) void gemm_bt_kernel(const u16* __restrict__ Xb,
                                                         const u16* __restrict__ Wb,
                                                         const float* __restrict__ bias,
                                                         float* __restrict__ out) {
    extern __shared__ __align__(16) char smem[];   // 131072 B
    const int K = D_IN, N = D_OUT;

    int bid = blockIdx.x;                  // 512 blocks
    int swz = (bid & 7) * 64 + (bid >> 3); // XCD swizzle, bijective (512 % 8 == 0)
    int tM = swz >> 4;                     // 32 M-tiles
    int tN = swz & 15;                     // 16 N-tiles

    int t = threadIdx.x;
    int lane = t & 63;
    int wave = t >> 6;
    int wm = wave >> 2;                    // 0..1
    int wn = wave & 3;                     // 0..3
    int l31 = lane & 31;
    int hi5 = lane >> 5;
    int l7 = lane & 7;

    // Swizzled 16B-slot byte offsets for kstep ks: global slot (2*ks+hi5),
    // stored at slot ^ (row&7); row&7 == l7 for all our frag rows.
    int xsl[4];
    #pragma unroll
    for (int ks = 0; ks < 4; ++ks) xsl[ks] = ((2 * ks + hi5) ^ l7) << 4;
    int aRowB = (wm * 128 + l31) * 128;    // + mblk*4096
    int bRowB = (wn * 64 + l31) * 128;     // + nf*4096

    // Staging: 4 regions x 2 rounds; thread t handles chunk j*512+t of each.
    // Regions (rows): A-mf01={0-63,128-191} A-mf23=+64
    //                 B-nf0={0-31,64-95,128-159,192-223} B-nf1=+32
    // LDS dest linear (row*128+slot*16); global source slot pre-XORed (rule 21).
    const u16 *srcA03[2], *srcA47[2], *srcB01[2], *srcB23[2];
    int ldsA03[2], ldsA47[2], ldsB01[2], ldsB23[2];
    #pragma unroll
    for (int j = 0; j < 2; ++j) {
        int idx = j * 512 + t;
        int rl = idx >> 3, slot = idx & 7;
        int rA = (rl & 63) + ((rl >> 6) << 7);
        int rB = (rl & 31) + ((rl >> 5) << 6);
        int r = rA;
        ldsA03[j] = r * 128 + slot * 16;
        srcA03[j] = Xb + (size_t)(tM * 256 + r) * K + ((slot ^ (r & 7)) << 3);
        r = rA + 64;
        ldsA47[j] = r * 128 + slot * 16;
        srcA47[j] = Xb + (size_t)(tM * 256 + r) * K + ((slot ^ (r & 7)) << 3);
        r = rB;
        ldsB01[j] = r * 128 + slot * 16;
        srcB01[j] = Wb + (size_t)(tN * 256 + r) * K + ((slot ^ (r & 7)) << 3);
        r = rB + 32;
        ldsB23[j] = r * 128 + slot * 16;
        srcB23[j] = Wb + (size_t)(tN * 256 + r) * K + ((slot ^ (r & 7)) << 3);
    }

    f32x16 acc[4][2];
    #pragma unroll
    for (int i = 0; i < 4; ++i)
        #pragma unroll
        for (int j = 0; j < 2; ++j)
            acc[i][j] = (f32x16){0.f,0.f,0.f,0.f,0.f,0.f,0.f,0.f,
                                 0.f,0.f,0.f,0.f,0.f,0.f,0.f,0.f};

    // prologue: stage tile0 -> buf0, tile1 -> buf1; wait tile0; preload nf0(t0)
    STAGE_R(srcA03, ldsA03, 0, 0);     STAGE_R(srcA47, ldsA47, 0, 0);
    STAGE_R(srcB01, ldsB01, 65536, 0); STAGE_R(srcB23, ldsB23, 65536, 0);
    STAGE_R(srcA03, ldsA03, 32768, 1); STAGE_R(srcA47, ldsA47, 32768, 1);
    STAGE_R(srcB01, ldsB01, 98304, 1); STAGE_R(srcB23, ldsB23, 98304, 1);
    asm volatile("s_waitcnt vmcnt(8)" ::: "memory");
    __builtin_amdgcn_s_barrier();

    bf16x8 a[2][4], bnf0[4], bnf1[4];
    #pragma unroll
    for (int ks = 0; ks < 4; ++ks)
        bnf0[ks] = *(const bf16x8*)(smem + 65536 + bRowB + xsl[ks]);

    for (int tt = 0; tt < NT; ++tt) {
        int pA = (tt & 1) * 32768;
        int pB = 65536 + (tt & 1) * 32768;
        int pBn = 65536 + ((~tt) & 1) * 32768;
        bool pre = (tt + 2 < NT);

        // ---- P1: read a[mf01] (8); MFMA (mf01, nf0) with preloaded bnf0
        #pragma unroll
        for (int m = 0; m < 2; ++m)
            #pragma unroll
            for (int ks = 0; ks < 4; ++ks)
                a[m][ks] = *(const bf16x8*)(smem + pA + aRowB + m * 4096 + xsl[ks]);
        asm volatile("s_waitcnt lgkmcnt(8)" ::: "memory");   // 12 outstanding
        __builtin_amdgcn_s_barrier();
        asm volatile("s_waitcnt lgkmcnt(0)");
        __builtin_amdgcn_s_setprio(1);
        #pragma unroll
        for (int m = 0; m < 2; ++m)
            #pragma unroll
            for (int ks = 0; ks < 4; ++ks)
                MFMA32(acc[m][0], a[m][ks], bnf0[ks]);
        __builtin_amdgcn_s_setprio(0);
        __builtin_amdgcn_s_barrier();

        // ---- P2: read bnf1 (4); stage A-mf01(tt+2) + B-nf0(tt+2); MFMA (mf01, nf1)
        #pragma unroll
        for (int ks = 0; ks < 4; ++ks)
            bnf1[ks] = *(const bf16x8*)(smem + pB + bRowB + 4096 + xsl[ks]);
        if (pre) {
            STAGE_R(srcA03, ldsA03, pA, tt + 2);
            STAGE_R(srcB01, ldsB01, pB, tt + 2);
        }
        __builtin_amdgcn_s_barrier();
        asm volatile("s_waitcnt lgkmcnt(0)");
        __builtin_amdgcn_s_setprio(1);
        #pragma unroll
        for (int m = 0; m < 2; ++m)
            #pragma unroll
            for (int ks = 0; ks < 4; ++ks)
                MFMA32(acc[m][1], a[m][ks], bnf1[ks]);
        __builtin_amdgcn_s_setprio(0);
        __builtin_amdgcn_s_barrier();

        // ---- P3: read a[mf23] (8); stage B-nf1(tt+2); MFMA (mf23, nf0)
        #pragma unroll
        for (int m = 0; m < 2; ++m)
            #pragma unroll
            for (int ks = 0; ks < 4; ++ks)
                a[m][ks] = *(const bf16x8*)(smem + pA + aRowB + (m + 2) * 4096 + xsl[ks]);
        if (pre) { STAGE_R(srcB23, ldsB23, pB, tt + 2); }
        __builtin_amdgcn_s_barrier();
        asm volatile("s_waitcnt lgkmcnt(0)");
        __builtin_amdgcn_s_setprio(1);
        #pragma unroll
        for (int m = 0; m < 2; ++m)
            #pragma unroll
            for (int ks = 0; ks < 4; ++ks)
                MFMA32(acc[m + 2][0], a[m][ks], bnf0[ks]);
        __builtin_amdgcn_s_setprio(0);
        __builtin_amdgcn_s_barrier();

        // ---- P4: stage A-mf23(tt+2); vmcnt; barrier; preload bnf0(tt+1)
        //          (no wait); MFMA (mf23, nf1) with bnf1
        if (pre) { STAGE_R(srcA47, ldsA47, pA, tt + 2); }
        if (tt < NT - 2) { asm volatile("s_waitcnt vmcnt(8)" ::: "memory"); }
        else             { asm volatile("s_waitcnt vmcnt(0)" ::: "memory"); }
        __builtin_amdgcn_s_barrier();
        if (tt + 1 < NT) {
            #pragma unroll
            for (int ks = 0; ks < 4; ++ks)
                bnf0[ks] = *(const bf16x8*)(smem + pBn + bRowB + xsl[ks]);
        }
        __builtin_amdgcn_s_setprio(1);
        #pragma unroll
        for (int m = 0; m < 2; ++m)
            #pragma unroll
            for (int ks = 0; ks < 4; ++ks)
                MFMA32(acc[m + 2][1], a[m][ks], bnf1[ks]);
        __builtin_amdgcn_s_setprio(0);
        __builtin_amdgcn_s_barrier();
    }

    // epilogue: 32x32 C/D layout col=lane&31, row=(reg&3)+8*(reg>>2)+4*(lane>>5)
    #pragma unroll
    for (int nf = 0; nf < 2; ++nf) {
        int gn = tN * 256 + wn * 64 + nf * 32 + l31;
        float bs = bias[gn];
        #pragma unroll
        for (int m = 0; m < 4; ++m) {
            #pragma unroll
            for (int reg = 0; reg < 16; ++reg) {
                int gm = tM * 256 + wm * 128 + m * 32
                       + (reg & 3) + ((reg >> 2) << 3) + (hi5 << 2);
                out[(size_t)gm * N + gn] = acc[m][nf][reg] + bs;
            }
        }
    }
}

extern "C" void kernel_launch(void* const* d_in, const int* in_sizes, int n_in,
                              void* d_out, int out_size, void* d_ws, size_t ws_size,
                              hipStream_t stream) {
    (void)in_sizes; (void)n_in; (void)out_size; (void)ws_size;
    const float* x      = (const float*)d_in[0];
    const int*   qw     = (const int*)d_in[1];
    const float* wmin   = (const float*)d_in[2];
    const float* wscale = (const float*)d_in[3];
    const float* bias   = (const float*)d_in[4];
    const float* A      = (const float*)d_in[5];
    const float* Bm     = (const float*)d_in[6];
    float* out = (float*)d_out;

    u16* Wb = (u16*)d_ws;                         // 4096*4096*2 = 33.5 MB
    u16* Xb = Wb + (size_t)D_OUT * D_IN;          // 8192*4096*2 = 67.1 MB

    dequant_fold_kernel<<<D_OUT / OPB, 256, 0, stream>>>(qw, wmin, wscale, A, Bm, Wb);
    xcast_kernel<<<(M_TOT * D_IN) / (256 * 8), 256, 0, stream>>>(x, Xb);
    gemm_bt_kernel<<<(M_TOT / BM) * (D_OUT / BN), 512, 131072, stream>>>(Xb, Wb, bias, out);
}

// Round 7
// 299.115 us; speedup vs baseline: 1.1014x; 1.1014x over previous
//
#include <hip/hip_runtime.h>
#include <hip/hip_bf16.h>

typedef unsigned short u16;
typedef unsigned int u32;
typedef __bf16 bf16x8 __attribute__((ext_vector_type(8)));
typedef float f32x4 __attribute__((ext_vector_type(4)));
typedef u16 u16x4 __attribute__((ext_vector_type(4)));
typedef u16 u16x8 __attribute__((ext_vector_type(8)));

#define D_IN 4096
#define D_OUT 4096
#define M_TOT 8192
#define RANK_ 16

#define BM 256
#define BN 256
#define BK 64
#define NT (D_IN / BK)   // 64 K-tiles
#define OPB 2            // dequant rows per block

__device__ __forceinline__ u16 f2bf(float f) {
    union { float f; u32 u; } v; v.f = f;
    u32 u = v.u;
    u32 r = (u + 0x7FFFu + ((u >> 16) & 1u)) >> 16;  // round-to-nearest-even
    return (u16)r;
}

// W_eff[o,i] = q[o,i]*scale[o] + min[o] + 2*sum_r B[o,r]*A[r,i]  -> bf16
__global__ __launch_bounds__(256) void dequant_fold_kernel(
        const int* __restrict__ q, const float* __restrict__ wmin,
        const float* __restrict__ wscale, const float* __restrict__ A,
        const float* __restrict__ Bm, u16* __restrict__ Wb) {
    const int K = D_IN;
    int o0 = blockIdx.x * OPB;
    float s0 = wscale[o0], s1 = wscale[o0 + 1];
    float m0 = wmin[o0],   m1 = wmin[o0 + 1];
    float Br0[RANK_], Br1[RANK_];   // block-uniform -> SGPRs
    #pragma unroll
    for (int r = 0; r < RANK_; ++r) {
        Br0[r] = 2.0f * Bm[(size_t)o0 * RANK_ + r];
        Br1[r] = 2.0f * Bm[(size_t)(o0 + 1) * RANK_ + r];
    }
    for (int i4 = threadIdx.x; i4 < K / 4; i4 += 256) {
        int i = i4 * 4;
        int4 q0 = *(const int4*)(q + (size_t)o0 * K + i);
        int4 q1 = *(const int4*)(q + (size_t)(o0 + 1) * K + i);
        float v00 = (float)q0.x * s0 + m0, v01 = (float)q0.y * s0 + m0;
        float v02 = (float)q0.z * s0 + m0, v03 = (float)q0.w * s0 + m0;
        float v10 = (float)q1.x * s1 + m1, v11 = (float)q1.y * s1 + m1;
        float v12 = (float)q1.z * s1 + m1, v13 = (float)q1.w * s1 + m1;
        #pragma unroll
        for (int r = 0; r < RANK_; ++r) {
            float4 av = *(const float4*)(A + (size_t)r * K + i);
            v00 += Br0[r] * av.x; v01 += Br0[r] * av.y;
            v02 += Br0[r] * av.z; v03 += Br0[r] * av.w;
            v10 += Br1[r] * av.x; v11 += Br1[r] * av.y;
            v12 += Br1[r] * av.z; v13 += Br1[r] * av.w;
        }
        u16x4 o0v, o1v;
        o0v.x = f2bf(v00); o0v.y = f2bf(v01); o0v.z = f2bf(v02); o0v.w = f2bf(v03);
        o1v.x = f2bf(v10); o1v.y = f2bf(v11); o1v.z = f2bf(v12); o1v.w = f2bf(v13);
        *(u16x4*)(Wb + (size_t)o0 * K + i) = o0v;
        *(u16x4*)(Wb + (size_t)(o0 + 1) * K + i) = o1v;
    }
}

// fp32 -> bf16, 8 elems/thread
__global__ void xcast_kernel(const float* __restrict__ x, u16* __restrict__ xb) {
    size_t i = (size_t)blockIdx.x * blockDim.x + threadIdx.x;
    const float4* p = (const float4*)x + i * 2;
    float4 a = p[0];
    float4 b = p[1];
    u16x8 o;
    o[0] = f2bf(a.x); o[1] = f2bf(a.y); o[2] = f2bf(a.z); o[3] = f2bf(a.w);
    o[4] = f2bf(b.x); o[5] = f2bf(b.y); o[6] = f2bf(b.z); o[7] = f2bf(b.w);
    *(u16x8*)(xb + i * 8) = o;
}

// ---- 256x256 8-phase GEMM (round-5 proven structure, 16x16x32 MFMA) ----
// Quadrant order (m03,n01)(m03,n23)(m47,n01)(m47,n23); b01 cross-tile
// preload at P4 (after vmcnt(8)+barrier), zero extra registers.
// Reads/phase: 8/4/8/4.  Staging EVENED to 2 loads/phase (m201 fidelity):
//   P1: B01(tt+2) [region free: b01 regs preloaded]   P2: A03(tt+2)
//   P3: B23(tt+2)                                     P4: A47(tt+2)
// vmcnt(8) once per tile = 8 newest (tile tt+2) stay in flight.

#define STAGE_R(sarr, larr, base, kt) do { _Pragma("unroll") \
    for (int j_ = 0; j_ < 2; ++j_) \
        __builtin_amdgcn_global_load_lds( \
            (__attribute__((address_space(1))) u32*)(sarr[j_] + (kt) * 64), \
            (__attribute__((address_space(3))) u32*)(smem + (base) + larr[j_]), \
            16, 0, 0); } while (0)

#define MFMA(d, va, vb) d = __builtin_amdgcn_mfma_f32_16x16x32_bf16(va, vb, d, 0, 0, 0)

__global__ __launch_bounds__(512, 2) void gemm_bt_kernel(const u16* __restrict__ Xb,
                                                         const u16* __restrict__ Wb,
                                                         const float* __restrict__ bias,
                                                         float* __restrict__ out) {
    extern __shared__ __align__(16) char smem[];   // 131072 B
    const int K = D_IN, N = D_OUT;

    int bid = blockIdx.x;                  // 512 blocks
    int swz = (bid & 7) * 64 + (bid >> 3); // XCD swizzle, bijective (512 % 8 == 0)
    int tM = swz >> 4;                     // 32 M-tiles
    int tN = swz & 15;                     // 16 N-tiles

    int t = threadIdx.x;
    int lane = t & 63;
    int wave = t >> 6;
    int wm = wave >> 2;                    // 0..1
    int wn = wave & 3;                     // 0..3
    int lr = lane & 15;
    int hi = lane >> 4;
    int l7 = lane & 7;

    // ds_read byte offsets: row*128 + swizzled 16B slot (slot ^= row&7).
    int xs0 = ((0 * 4 + hi) ^ l7) << 4;    // ks=0
    int xs1 = ((1 * 4 + hi) ^ l7) << 4;    // ks=1
    int aRow = (wm * 128 + lr) * 128;      // + mf*2048
    int bRow = (wn * 64 + lr) * 128;       // + nf*2048

    // Staging: 4 regions x 2 rounds; thread t handles chunk j*512+t of each.
    // Regions (rows): A03={0-63,128-191} A47=+64  B01={0-31,64-95,128-159,192-223} B23=+32
    // LDS dest linear (row*128+slot*16); global source slot pre-XORed (rule 21).
    const u16 *srcA03[2], *srcA47[2], *srcB01[2], *srcB23[2];
    int ldsA03[2], ldsA47[2], ldsB01[2], ldsB23[2];
    #pragma unroll
    for (int j = 0; j < 2; ++j) {
        int idx = j * 512 + t;
        int rl = idx >> 3, slot = idx & 7;
        int rA = (rl & 63) + ((rl >> 6) << 7);
        int rB = (rl & 31) + ((rl >> 5) << 6);
        int r = rA;
        ldsA03[j] = r * 128 + slot * 16;
        srcA03[j] = Xb + (size_t)(tM * 256 + r) * K + ((slot ^ (r & 7)) << 3);
        r = rA + 64;
        ldsA47[j] = r * 128 + slot * 16;
        srcA47[j] = Xb + (size_t)(tM * 256 + r) * K + ((slot ^ (r & 7)) << 3);
        r = rB;
        ldsB01[j] = r * 128 + slot * 16;
        srcB01[j] = Wb + (size_t)(tN * 256 + r) * K + ((slot ^ (r & 7)) << 3);
        r = rB + 32;
        ldsB23[j] = r * 128 + slot * 16;
        srcB23[j] = Wb + (size_t)(tN * 256 + r) * K + ((slot ^ (r & 7)) << 3);
    }

    f32x4 acc[8][4];
    #pragma unroll
    for (int i = 0; i < 8; ++i)
        #pragma unroll
        for (int j = 0; j < 4; ++j)
            acc[i][j] = (f32x4){0.f, 0.f, 0.f, 0.f};

    // prologue: stage tile0 -> buf0, tile1 -> buf1; wait tile0; preload b01(t0)
    STAGE_R(srcA03, ldsA03, 0, 0);     STAGE_R(srcA47, ldsA47, 0, 0);
    STAGE_R(srcB01, ldsB01, 65536, 0); STAGE_R(srcB23, ldsB23, 65536, 0);
    STAGE_R(srcA03, ldsA03, 32768, 1); STAGE_R(srcA47, ldsA47, 32768, 1);
    STAGE_R(srcB01, ldsB01, 98304, 1); STAGE_R(srcB23, ldsB23, 98304, 1);
    asm volatile("s_waitcnt vmcnt(8)" ::: "memory");
    __builtin_amdgcn_s_barrier();

    bf16x8 a[4][2], b23[2][2], b01[2][2];
    #pragma unroll
    for (int nf = 0; nf < 2; ++nf) {
        b01[nf][0] = *(const bf16x8*)(smem + 65536 + bRow + nf * 2048 + xs0);
        b01[nf][1] = *(const bf16x8*)(smem + 65536 + bRow + nf * 2048 + xs1);
    }

    for (int tt = 0; tt < NT; ++tt) {
        int pA = (tt & 1) * 32768;
        int pB = 65536 + (tt & 1) * 32768;
        int pBn = 65536 + ((~tt) & 1) * 32768;
        bool pre = (tt + 2 < NT);

        // ---- P1: read a03 (8); stage B01(tt+2); MFMA (m03, n01) with b01
        #pragma unroll
        for (int mf = 0; mf < 4; ++mf) {
            a[mf][0] = *(const bf16x8*)(smem + pA + aRow + mf * 2048 + xs0);
            a[mf][1] = *(const bf16x8*)(smem + pA + aRow + mf * 2048 + xs1);
        }
        if (pre) { STAGE_R(srcB01, ldsB01, pB, tt + 2); }
        asm volatile("s_waitcnt lgkmcnt(4)" ::: "memory");
        __builtin_amdgcn_s_barrier();
        asm volatile("s_waitcnt lgkmcnt(0)");
        __builtin_amdgcn_s_setprio(1);
        #pragma unroll
        for (int mf = 0; mf < 4; ++mf)
            #pragma unroll
            for (int nf = 0; nf < 2; ++nf) {
                MFMA(acc[mf][nf], a[mf][0], b01[nf][0]);
                MFMA(acc[mf][nf], a[mf][1], b01[nf][1]);
            }
        __builtin_amdgcn_s_setprio(0);
        __builtin_amdgcn_s_barrier();

        // ---- P2: read b23 (4); stage A03(tt+2); MFMA (m03, n23)
        #pragma unroll
        for (int nf = 0; nf < 2; ++nf) {
            b23[nf][0] = *(const bf16x8*)(smem + pB + bRow + (nf + 2) * 2048 + xs0);
            b23[nf][1] = *(const bf16x8*)(smem + pB + bRow + (nf + 2) * 2048 + xs1);
        }
        if (pre) { STAGE_R(srcA03, ldsA03, pA, tt + 2); }
        __builtin_amdgcn_s_barrier();
        asm volatile("s_waitcnt lgkmcnt(0)");
        __builtin_amdgcn_s_setprio(1);
        #pragma unroll
        for (int mf = 0; mf < 4; ++mf)
            #pragma unroll
            for (int nf = 0; nf < 2; ++nf) {
                MFMA(acc[mf][nf + 2], a[mf][0], b23[nf][0]);
                MFMA(acc[mf][nf + 2], a[mf][1], b23[nf][1]);
            }
        __builtin_amdgcn_s_setprio(0);
        __builtin_amdgcn_s_barrier();

        // ---- P3: read a47 (8); stage B23(tt+2); MFMA (m47, n01) with b01
        #pragma unroll
        for (int mf = 0; mf < 4; ++mf) {
            a[mf][0] = *(const bf16x8*)(smem + pA + aRow + (mf + 4) * 2048 + xs0);
            a[mf][1] = *(const bf16x8*)(smem + pA + aRow + (mf + 4) * 2048 + xs1);
        }
        if (pre) { STAGE_R(srcB23, ldsB23, pB, tt + 2); }
        asm volatile("s_waitcnt lgkmcnt(4)" ::: "memory");
        __builtin_amdgcn_s_barrier();
        asm volatile("s_waitcnt lgkmcnt(0)");
        __builtin_amdgcn_s_setprio(1);
        #pragma unroll
        for (int mf = 0; mf < 4; ++mf)
            #pragma unroll
            for (int nf = 0; nf < 2; ++nf) {
                MFMA(acc[mf + 4][nf], a[mf][0], b01[nf][0]);
                MFMA(acc[mf + 4][nf], a[mf][1], b01[nf][1]);
            }
        __builtin_amdgcn_s_setprio(0);
        __builtin_amdgcn_s_barrier();

        // ---- P4: stage A47(tt+2); vmcnt; barrier; preload b01(tt+1) (no wait);
        //          MFMA (m47, n23) with b23
        if (pre) { STAGE_R(srcA47, ldsA47, pA, tt + 2); }
        if (tt < NT - 2) { asm volatile("s_waitcnt vmcnt(8)" ::: "memory"); }
        else             { asm volatile("s_waitcnt vmcnt(0)" ::: "memory"); }
        __builtin_amdgcn_s_barrier();
        if (tt + 1 < NT) {
            #pragma unroll
            for (int nf = 0; nf < 2; ++nf) {
                b01[nf][0] = *(const bf16x8*)(smem + pBn + bRow + nf * 2048 + xs0);
                b01[nf][1] = *(const bf16x8*)(smem + pBn + bRow + nf * 2048 + xs1);
            }
        }
        __builtin_amdgcn_s_setprio(1);
        #pragma unroll
        for (int mf = 0; mf < 4; ++mf)
            #pragma unroll
            for (int nf = 0; nf < 2; ++nf) {
                MFMA(acc[mf + 4][nf + 2], a[mf][0], b23[nf][0]);
                MFMA(acc[mf + 4][nf + 2], a[mf][1], b23[nf][1]);
            }
        __builtin_amdgcn_s_setprio(0);
        __builtin_amdgcn_s_barrier();
    }

    // epilogue: C/D layout col=lane&15, row=(lane>>4)*4+reg
    #pragma unroll
    for (int nf = 0; nf < 4; ++nf) {
        int gn = tN * 256 + wn * 64 + nf * 16 + lr;
        float bs = bias[gn];
        #pragma unroll
        for (int mf = 0; mf < 8; ++mf) {
            #pragma unroll
            for (int r = 0; r < 4; ++r) {
                int gm = tM * 256 + wm * 128 + mf * 16 + hi * 4 + r;
                out[(size_t)gm * N + gn] = acc[mf][nf][r] + bs;
            }
        }
    }
}

extern "C" void kernel_launch(void* const* d_in, const int* in_sizes, int n_in,
                              void* d_out, int out_size, void* d_ws, size_t ws_size,
                              hipStream_t stream) {
    (void)in_sizes; (void)n_in; (void)out_size; (void)ws_size;
    const float* x      = (const float*)d_in[0];
    const int*   qw     = (const int*)d_in[1];
    const float* wmin   = (const float*)d_in[2];
    const float* wscale = (const float*)d_in[3];
    const float* bias   = (const float*)d_in[4];
    const float* A      = (const float*)d_in[5];
    const float* Bm     = (const float*)d_in[6];
    float* out = (float*)d_out;

    u16* Wb = (u16*)d_ws;                         // 4096*4096*2 = 33.5 MB
    u16* Xb = Wb + (size_t)D_OUT * D_IN;          // 8192*4096*2 = 67.1 MB

    dequant_fold_kernel<<<D_OUT / OPB, 256, 0, stream>>>(qw, wmin, wscale, A, Bm, Wb);
    xcast_kernel<<<(M_TOT * D_IN) / (256 * 8), 256, 0, stream>>>(x, Xb);
    gemm_bt_kernel<<<(M_TOT / BM) * (D_OUT / BN), 512, 131072, stream>>>(Xb, Wb, bias, out);
}

// Round 8
// 298.732 us; speedup vs baseline: 1.1028x; 1.0013x over previous
//
#include <hip/hip_runtime.h>
#include <hip/hip_bf16.h>

typedef unsigned short u16;
typedef unsigned int u32;
typedef __bf16 bf16x8 __attribute__((ext_vector_type(8)));
typedef float f32x4 __attribute__((ext_vector_type(4)));
typedef int i32x4 __attribute__((ext_vector_type(4)));
typedef u16 u16x4 __attribute__((ext_vector_type(4)));
typedef u16 u16x8 __attribute__((ext_vector_type(8)));

#define D_IN 4096
#define D_OUT 4096
#define M_TOT 8192
#define RANK_ 16

#define BM 256
#define BN 256
#define BK 64
#define NT (D_IN / BK)   // 64 K-tiles
#define OPB 2            // dequant rows per block

__device__ __forceinline__ u16 f2bf(float f) {
    union { float f; u32 u; } v; v.f = f;
    u32 u = v.u;
    u32 r = (u + 0x7FFFu + ((u >> 16) & 1u)) >> 16;  // round-to-nearest-even
    return (u16)r;
}

// W_eff[o,i] = q[o,i]*scale[o] + min[o] + 2*sum_r B[o,r]*A[r,i]  -> bf16
// q is single-pass -> non-temporal load (keep L3 for Wb/Xb operand panels).
__global__ __launch_bounds__(256) void dequant_fold_kernel(
        const int* __restrict__ q, const float* __restrict__ wmin,
        const float* __restrict__ wscale, const float* __restrict__ A,
        const float* __restrict__ Bm, u16* __restrict__ Wb) {
    const int K = D_IN;
    int o0 = blockIdx.x * OPB;
    float s0 = wscale[o0], s1 = wscale[o0 + 1];
    float m0 = wmin[o0],   m1 = wmin[o0 + 1];
    float Br0[RANK_], Br1[RANK_];   // block-uniform -> SGPRs
    #pragma unroll
    for (int r = 0; r < RANK_; ++r) {
        Br0[r] = 2.0f * Bm[(size_t)o0 * RANK_ + r];
        Br1[r] = 2.0f * Bm[(size_t)(o0 + 1) * RANK_ + r];
    }
    for (int i4 = threadIdx.x; i4 < K / 4; i4 += 256) {
        int i = i4 * 4;
        i32x4 q0 = __builtin_nontemporal_load((const i32x4*)(q + (size_t)o0 * K + i));
        i32x4 q1 = __builtin_nontemporal_load((const i32x4*)(q + (size_t)(o0 + 1) * K + i));
        float v00 = (float)q0.x * s0 + m0, v01 = (float)q0.y * s0 + m0;
        float v02 = (float)q0.z * s0 + m0, v03 = (float)q0.w * s0 + m0;
        float v10 = (float)q1.x * s1 + m1, v11 = (float)q1.y * s1 + m1;
        float v12 = (float)q1.z * s1 + m1, v13 = (float)q1.w * s1 + m1;
        #pragma unroll
        for (int r = 0; r < RANK_; ++r) {
            f32x4 av = *(const f32x4*)(A + (size_t)r * K + i);
            v00 += Br0[r] * av.x; v01 += Br0[r] * av.y;
            v02 += Br0[r] * av.z; v03 += Br0[r] * av.w;
            v10 += Br1[r] * av.x; v11 += Br1[r] * av.y;
            v12 += Br1[r] * av.z; v13 += Br1[r] * av.w;
        }
        u16x4 o0v, o1v;
        o0v.x = f2bf(v00); o0v.y = f2bf(v01); o0v.z = f2bf(v02); o0v.w = f2bf(v03);
        o1v.x = f2bf(v10); o1v.y = f2bf(v11); o1v.z = f2bf(v12); o1v.w = f2bf(v13);
        *(u16x4*)(Wb + (size_t)o0 * K + i) = o0v;
        *(u16x4*)(Wb + (size_t)(o0 + 1) * K + i) = o1v;
    }
}

// fp32 -> bf16, 8 elems/thread; x is single-pass -> non-temporal load
__global__ void xcast_kernel(const float* __restrict__ x, u16* __restrict__ xb) {
    size_t i = (size_t)blockIdx.x * blockDim.x + threadIdx.x;
    const f32x4* p = (const f32x4*)x + i * 2;
    f32x4 a = __builtin_nontemporal_load(p);
    f32x4 b = __builtin_nontemporal_load(p + 1);
    u16x8 o;
    o[0] = f2bf(a.x); o[1] = f2bf(a.y); o[2] = f2bf(a.z); o[3] = f2bf(a.w);
    o[4] = f2bf(b.x); o[5] = f2bf(b.y); o[6] = f2bf(b.z); o[7] = f2bf(b.w);
    *(u16x8*)(xb + i * 8) = o;
}

// ---- 256x256 8-phase GEMM (round-7 proven structure, 16x16x32 MFMA) ----
// Quadrant order (m03,n01)(m03,n23)(m47,n01)(m47,n23); b01 cross-tile
// preload at P4 (after vmcnt(8)+barrier), zero extra registers.
// Reads/phase: 8/4/8/4.  Staging 2 loads/phase:
//   P1: B01(tt+2)  P2: A03(tt+2)  P3: B23(tt+2)  P4: A47(tt+2)
// vmcnt(8) once per tile = 8 newest (tile tt+2) stay in flight.
// Epilogue uses NON-TEMPORAL stores: out is write-once; keeping it out of
// L3 preserves residency for the reused Xb/Wb panels (FETCH was 3x ideal).

#define STAGE_R(sarr, larr, base, kt) do { _Pragma("unroll") \
    for (int j_ = 0; j_ < 2; ++j_) \
        __builtin_amdgcn_global_load_lds( \
            (__attribute__((address_space(1))) u32*)(sarr[j_] + (kt) * 64), \
            (__attribute__((address_space(3))) u32*)(smem + (base) + larr[j_]), \
            16, 0, 0); } while (0)

#define MFMA(d, va, vb) d = __builtin_amdgcn_mfma_f32_16x16x32_bf16(va, vb, d, 0, 0, 0)

__global__ __launch_bounds__(512, 2) void gemm_bt_kernel(const u16* __restrict__ Xb,
                                                         const u16* __restrict__ Wb,
                                                         const float* __restrict__ bias,
                                                         float* __restrict__ out) {
    extern __shared__ __align__(16) char smem[];   // 131072 B
    const int K = D_IN, N = D_OUT;

    int bid = blockIdx.x;                  // 512 blocks
    int swz = (bid & 7) * 64 + (bid >> 3); // XCD swizzle, bijective (512 % 8 == 0)
    int tM = swz >> 4;                     // 32 M-tiles
    int tN = swz & 15;                     // 16 N-tiles

    int t = threadIdx.x;
    int lane = t & 63;
    int wave = t >> 6;
    int wm = wave >> 2;                    // 0..1
    int wn = wave & 3;                     // 0..3
    int lr = lane & 15;
    int hi = lane >> 4;
    int l7 = lane & 7;

    // ds_read byte offsets: row*128 + swizzled 16B slot (slot ^= row&7).
    int xs0 = ((0 * 4 + hi) ^ l7) << 4;    // ks=0
    int xs1 = ((1 * 4 + hi) ^ l7) << 4;    // ks=1
    int aRow = (wm * 128 + lr) * 128;      // + mf*2048
    int bRow = (wn * 64 + lr) * 128;       // + nf*2048

    // Staging: 4 regions x 2 rounds; thread t handles chunk j*512+t of each.
    // Regions (rows): A03={0-63,128-191} A47=+64  B01={0-31,64-95,128-159,192-223} B23=+32
    // LDS dest linear (row*128+slot*16); global source slot pre-XORed (rule 21).
    const u16 *srcA03[2], *srcA47[2], *srcB01[2], *srcB23[2];
    int ldsA03[2], ldsA47[2], ldsB01[2], ldsB23[2];
    #pragma unroll
    for (int j = 0; j < 2; ++j) {
        int idx = j * 512 + t;
        int rl = idx >> 3, slot = idx & 7;
        int rA = (rl & 63) + ((rl >> 6) << 7);
        int rB = (rl & 31) + ((rl >> 5) << 6);
        int r = rA;
        ldsA03[j] = r * 128 + slot * 16;
        srcA03[j] = Xb + (size_t)(tM * 256 + r) * K + ((slot ^ (r & 7)) << 3);
        r = rA + 64;
        ldsA47[j] = r * 128 + slot * 16;
        srcA47[j] = Xb + (size_t)(tM * 256 + r) * K + ((slot ^ (r & 7)) << 3);
        r = rB;
        ldsB01[j] = r * 128 + slot * 16;
        srcB01[j] = Wb + (size_t)(tN * 256 + r) * K + ((slot ^ (r & 7)) << 3);
        r = rB + 32;
        ldsB23[j] = r * 128 + slot * 16;
        srcB23[j] = Wb + (size_t)(tN * 256 + r) * K + ((slot ^ (r & 7)) << 3);
    }

    f32x4 acc[8][4];
    #pragma unroll
    for (int i = 0; i < 8; ++i)
        #pragma unroll
        for (int j = 0; j < 4; ++j)
            acc[i][j] = (f32x4){0.f, 0.f, 0.f, 0.f};

    // prologue: stage tile0 -> buf0, tile1 -> buf1; wait tile0; preload b01(t0)
    STAGE_R(srcA03, ldsA03, 0, 0);     STAGE_R(srcA47, ldsA47, 0, 0);
    STAGE_R(srcB01, ldsB01, 65536, 0); STAGE_R(srcB23, ldsB23, 65536, 0);
    STAGE_R(srcA03, ldsA03, 32768, 1); STAGE_R(srcA47, ldsA47, 32768, 1);
    STAGE_R(srcB01, ldsB01, 98304, 1); STAGE_R(srcB23, ldsB23, 98304, 1);
    asm volatile("s_waitcnt vmcnt(8)" ::: "memory");
    __builtin_amdgcn_s_barrier();

    bf16x8 a[4][2], b23[2][2], b01[2][2];
    #pragma unroll
    for (int nf = 0; nf < 2; ++nf) {
        b01[nf][0] = *(const bf16x8*)(smem + 65536 + bRow + nf * 2048 + xs0);
        b01[nf][1] = *(const bf16x8*)(smem + 65536 + bRow + nf * 2048 + xs1);
    }

    for (int tt = 0; tt < NT; ++tt) {
        int pA = (tt & 1) * 32768;
        int pB = 65536 + (tt & 1) * 32768;
        int pBn = 65536 + ((~tt) & 1) * 32768;
        bool pre = (tt + 2 < NT);

        // ---- P1: read a03 (8); stage B01(tt+2); MFMA (m03, n01) with b01
        #pragma unroll
        for (int mf = 0; mf < 4; ++mf) {
            a[mf][0] = *(const bf16x8*)(smem + pA + aRow + mf * 2048 + xs0);
            a[mf][1] = *(const bf16x8*)(smem + pA + aRow + mf * 2048 + xs1);
        }
        if (pre) { STAGE_R(srcB01, ldsB01, pB, tt + 2); }
        asm volatile("s_waitcnt lgkmcnt(4)" ::: "memory");
        __builtin_amdgcn_s_barrier();
        asm volatile("s_waitcnt lgkmcnt(0)");
        __builtin_amdgcn_s_setprio(1);
        #pragma unroll
        for (int mf = 0; mf < 4; ++mf)
            #pragma unroll
            for (int nf = 0; nf < 2; ++nf) {
                MFMA(acc[mf][nf], a[mf][0], b01[nf][0]);
                MFMA(acc[mf][nf], a[mf][1], b01[nf][1]);
            }
        __builtin_amdgcn_s_setprio(0);
        __builtin_amdgcn_s_barrier();

        // ---- P2: read b23 (4); stage A03(tt+2); MFMA (m03, n23)
        #pragma unroll
        for (int nf = 0; nf < 2; ++nf) {
            b23[nf][0] = *(const bf16x8*)(smem + pB + bRow + (nf + 2) * 2048 + xs0);
            b23[nf][1] = *(const bf16x8*)(smem + pB + bRow + (nf + 2) * 2048 + xs1);
        }
        if (pre) { STAGE_R(srcA03, ldsA03, pA, tt + 2); }
        __builtin_amdgcn_s_barrier();
        asm volatile("s_waitcnt lgkmcnt(0)");
        __builtin_amdgcn_s_setprio(1);
        #pragma unroll
        for (int mf = 0; mf < 4; ++mf)
            #pragma unroll
            for (int nf = 0; nf < 2; ++nf) {
                MFMA(acc[mf][nf + 2], a[mf][0], b23[nf][0]);
                MFMA(acc[mf][nf + 2], a[mf][1], b23[nf][1]);
            }
        __builtin_amdgcn_s_setprio(0);
        __builtin_amdgcn_s_barrier();

        // ---- P3: read a47 (8); stage B23(tt+2); MFMA (m47, n01) with b01
        #pragma unroll
        for (int mf = 0; mf < 4; ++mf) {
            a[mf][0] = *(const bf16x8*)(smem + pA + aRow + (mf + 4) * 2048 + xs0);
            a[mf][1] = *(const bf16x8*)(smem + pA + aRow + (mf + 4) * 2048 + xs1);
        }
        if (pre) { STAGE_R(srcB23, ldsB23, pB, tt + 2); }
        asm volatile("s_waitcnt lgkmcnt(4)" ::: "memory");
        __builtin_amdgcn_s_barrier();
        asm volatile("s_waitcnt lgkmcnt(0)");
        __builtin_amdgcn_s_setprio(1);
        #pragma unroll
        for (int mf = 0; mf < 4; ++mf)
            #pragma unroll
            for (int nf = 0; nf < 2; ++nf) {
                MFMA(acc[mf + 4][nf], a[mf][0], b01[nf][0]);
                MFMA(acc[mf + 4][nf], a[mf][1], b01[nf][1]);
            }
        __builtin_amdgcn_s_setprio(0);
        __builtin_amdgcn_s_barrier();

        // ---- P4: stage A47(tt+2); vmcnt; barrier; preload b01(tt+1) (no wait);
        //          MFMA (m47, n23) with b23
        if (pre) { STAGE_R(srcA47, ldsA47, pA, tt + 2); }
        if (tt < NT - 2) { asm volatile("s_waitcnt vmcnt(8)" ::: "memory"); }
        else             { asm volatile("s_waitcnt vmcnt(0)" ::: "memory"); }
        __builtin_amdgcn_s_barrier();
        if (tt + 1 < NT) {
            #pragma unroll
            for (int nf = 0; nf < 2; ++nf) {
                b01[nf][0] = *(const bf16x8*)(smem + pBn + bRow + nf * 2048 + xs0);
                b01[nf][1] = *(const bf16x8*)(smem + pBn + bRow + nf * 2048 + xs1);
            }
        }
        __builtin_amdgcn_s_setprio(1);
        #pragma unroll
        for (int mf = 0; mf < 4; ++mf)
            #pragma unroll
            for (int nf = 0; nf < 2; ++nf) {
                MFMA(acc[mf + 4][nf + 2], a[mf][0], b23[nf][0]);
                MFMA(acc[mf + 4][nf + 2], a[mf][1], b23[nf][1]);
            }
        __builtin_amdgcn_s_setprio(0);
        __builtin_amdgcn_s_barrier();
    }

    // epilogue: C/D layout col=lane&15, row=(lane>>4)*4+reg; non-temporal
    // stores keep the 134 MB write stream out of L3.
    #pragma unroll
    for (int nf = 0; nf < 4; ++nf) {
        int gn = tN * 256 + wn * 64 + nf * 16 + lr;
        float bs = bias[gn];
        #pragma unroll
        for (int mf = 0; mf < 8; ++mf) {
            #pragma unroll
            for (int r = 0; r < 4; ++r) {
                int gm = tM * 256 + wm * 128 + mf * 16 + hi * 4 + r;
                __builtin_nontemporal_store(acc[mf][nf][r] + bs,
                                            &out[(size_t)gm * N + gn]);
            }
        }
    }
}

extern "C" void kernel_launch(void* const* d_in, const int* in_sizes, int n_in,
                              void* d_out, int out_size, void* d_ws, size_t ws_size,
                              hipStream_t stream) {
    (void)in_sizes; (void)n_in; (void)out_size; (void)ws_size;
    const float* x      = (const float*)d_in[0];
    const int*   qw     = (const int*)d_in[1];
    const float* wmin   = (const float*)d_in[2];
    const float* wscale = (const float*)d_in[3];
    const float* bias   = (const float*)d_in[4];
    const float* A      = (const float*)d_in[5];
    const float* Bm     = (const float*)d_in[6];
    float* out = (float*)d_out;

    u16* Wb = (u16*)d_ws;                         // 4096*4096*2 = 33.5 MB
    u16* Xb = Wb + (size_t)D_OUT * D_IN;          // 8192*4096*2 = 67.1 MB

    dequant_fold_kernel<<<D_OUT / OPB, 256, 0, stream>>>(qw, wmin, wscale, A, Bm, Wb);
    xcast_kernel<<<(M_TOT * D_IN) / (256 * 8), 256, 0, stream>>>(x, Xb);
    gemm_bt_kernel<<<(M_TOT / BM) * (D_OUT / BN), 512, 131072, stream>>>(Xb, Wb, bias, out);
}

// Round 9
// 291.549 us; speedup vs baseline: 1.1300x; 1.0246x over previous
//
#include <hip/hip_runtime.h>
#include <hip/hip_bf16.h>

typedef unsigned short u16;
typedef unsigned int u32;
typedef __bf16 bf16x8 __attribute__((ext_vector_type(8)));
typedef float f32x4 __attribute__((ext_vector_type(4)));
typedef int i32x4 __attribute__((ext_vector_type(4)));
typedef u16 u16x4 __attribute__((ext_vector_type(4)));
typedef u16 u16x8 __attribute__((ext_vector_type(8)));

#define D_IN 4096
#define D_OUT 4096
#define M_TOT 8192
#define RANK_ 16

#define BM 256
#define BN 256
#define BK 64
#define NT (D_IN / BK)   // 64 K-tiles
#define OPB 2            // dequant rows per block

__device__ __forceinline__ u16 f2bf(float f) {
    union { float f; u32 u; } v; v.f = f;
    u32 u = v.u;
    u32 r = (u + 0x7FFFu + ((u >> 16) & 1u)) >> 16;  // round-to-nearest-even
    return (u16)r;
}

// W_eff[o,i] = q[o,i]*scale[o] + min[o] + 2*sum_r B[o,r]*A[r,i]  -> bf16
__global__ __launch_bounds__(256) void dequant_fold_kernel(
        const int* __restrict__ q, const float* __restrict__ wmin,
        const float* __restrict__ wscale, const float* __restrict__ A,
        const float* __restrict__ Bm, u16* __restrict__ Wb) {
    const int K = D_IN;
    int o0 = blockIdx.x * OPB;
    float s0 = wscale[o0], s1 = wscale[o0 + 1];
    float m0 = wmin[o0],   m1 = wmin[o0 + 1];
    float Br0[RANK_], Br1[RANK_];   // block-uniform -> SGPRs
    #pragma unroll
    for (int r = 0; r < RANK_; ++r) {
        Br0[r] = 2.0f * Bm[(size_t)o0 * RANK_ + r];
        Br1[r] = 2.0f * Bm[(size_t)(o0 + 1) * RANK_ + r];
    }
    for (int i4 = threadIdx.x; i4 < K / 4; i4 += 256) {
        int i = i4 * 4;
        i32x4 q0 = __builtin_nontemporal_load((const i32x4*)(q + (size_t)o0 * K + i));
        i32x4 q1 = __builtin_nontemporal_load((const i32x4*)(q + (size_t)(o0 + 1) * K + i));
        float v00 = (float)q0.x * s0 + m0, v01 = (float)q0.y * s0 + m0;
        float v02 = (float)q0.z * s0 + m0, v03 = (float)q0.w * s0 + m0;
        float v10 = (float)q1.x * s1 + m1, v11 = (float)q1.y * s1 + m1;
        float v12 = (float)q1.z * s1 + m1, v13 = (float)q1.w * s1 + m1;
        #pragma unroll
        for (int r = 0; r < RANK_; ++r) {
            f32x4 av = *(const f32x4*)(A + (size_t)r * K + i);
            v00 += Br0[r] * av.x; v01 += Br0[r] * av.y;
            v02 += Br0[r] * av.z; v03 += Br0[r] * av.w;
            v10 += Br1[r] * av.x; v11 += Br1[r] * av.y;
            v12 += Br1[r] * av.z; v13 += Br1[r] * av.w;
        }
        u16x4 o0v, o1v;
        o0v.x = f2bf(v00); o0v.y = f2bf(v01); o0v.z = f2bf(v02); o0v.w = f2bf(v03);
        o1v.x = f2bf(v10); o1v.y = f2bf(v11); o1v.z = f2bf(v12); o1v.w = f2bf(v13);
        *(u16x4*)(Wb + (size_t)o0 * K + i) = o0v;
        *(u16x4*)(Wb + (size_t)(o0 + 1) * K + i) = o1v;
    }
}

// fp32 -> bf16, 8 elems/thread; x is single-pass -> non-temporal load
__global__ void xcast_kernel(const float* __restrict__ x, u16* __restrict__ xb) {
    size_t i = (size_t)blockIdx.x * blockDim.x + threadIdx.x;
    const f32x4* p = (const f32x4*)x + i * 2;
    f32x4 a = __builtin_nontemporal_load(p);
    f32x4 b = __builtin_nontemporal_load(p + 1);
    u16x8 o;
    o[0] = f2bf(a.x); o[1] = f2bf(a.y); o[2] = f2bf(a.z); o[3] = f2bf(a.w);
    o[4] = f2bf(b.x); o[5] = f2bf(b.y); o[6] = f2bf(b.z); o[7] = f2bf(b.w);
    *(u16x8*)(xb + i * 8) = o;
}

// ---- 256x256 8-phase GEMM, pipelined reads (12/0/8/4) ----
// Quadrant order (m03,n01)(m03,n23)(m47,n01)(m47,n23).
// Cross-phase pipelining at ZERO register cost:
//   - b01 (used P1,P3) preloaded at PREV tile's P4 (after vmcnt+barrier)
//   - b23 (used P2,P4) read at P1; its 4 reads complete under P1's MFMA
//     (race-free: region staged at P3(tt-2), landed by P4(tt-1) vmcnt;
//      all waves' reads done before P2 post-barrier < P3 stage issue)
// Waits: P1 pre-MFMA lgkmcnt(4) (b23 floats), P2 lgkm(0) instant,
//        P3 lgkm(0) (a47 exposed), P4 none.
// Staging 2 loads/phase: P1 B01(tt+2), P2 A03, P3 B23, P4 A47;
// vmcnt(8) once per tile (8 newest = tile tt+2 stay in flight).

#define STAGE_R(sarr, larr, base, kt) do { _Pragma("unroll") \
    for (int j_ = 0; j_ < 2; ++j_) \
        __builtin_amdgcn_global_load_lds( \
            (__attribute__((address_space(1))) u32*)(sarr[j_] + (kt) * 64), \
            (__attribute__((address_space(3))) u32*)(smem + (base) + larr[j_]), \
            16, 0, 0); } while (0)

#define MFMA(d, va, vb) d = __builtin_amdgcn_mfma_f32_16x16x32_bf16(va, vb, d, 0, 0, 0)

__global__ __launch_bounds__(512, 2) void gemm_bt_kernel(const u16* __restrict__ Xb,
                                                         const u16* __restrict__ Wb,
                                                         const float* __restrict__ bias,
                                                         float* __restrict__ out) {
    extern __shared__ __align__(16) char smem[];   // 131072 B
    const int K = D_IN, N = D_OUT;

    int bid = blockIdx.x;                  // 512 blocks
    int swz = (bid & 7) * 64 + (bid >> 3); // XCD swizzle, bijective (512 % 8 == 0)
    int tM = swz >> 4;                     // 32 M-tiles
    int tN = swz & 15;                     // 16 N-tiles

    int t = threadIdx.x;
    int lane = t & 63;
    int wave = t >> 6;
    int wm = wave >> 2;                    // 0..1
    int wn = wave & 3;                     // 0..3
    int lr = lane & 15;
    int hi = lane >> 4;
    int l7 = lane & 7;

    // ds_read byte offsets: row*128 + swizzled 16B slot (slot ^= row&7).
    int xs0 = ((0 * 4 + hi) ^ l7) << 4;    // ks=0
    int xs1 = ((1 * 4 + hi) ^ l7) << 4;    // ks=1
    int aRow = (wm * 128 + lr) * 128;      // + mf*2048
    int bRow = (wn * 64 + lr) * 128;       // + nf*2048

    // Staging: 4 regions x 2 rounds; thread t handles chunk j*512+t of each.
    // Regions (rows): A03={0-63,128-191} A47=+64  B01={0-31,64-95,128-159,192-223} B23=+32
    // LDS dest linear (row*128+slot*16); global source slot pre-XORed (rule 21).
    const u16 *srcA03[2], *srcA47[2], *srcB01[2], *srcB23[2];
    int ldsA03[2], ldsA47[2], ldsB01[2], ldsB23[2];
    #pragma unroll
    for (int j = 0; j < 2; ++j) {
        int idx = j * 512 + t;
        int rl = idx >> 3, slot = idx & 7;
        int rA = (rl & 63) + ((rl >> 6) << 7);
        int rB = (rl & 31) + ((rl >> 5) << 6);
        int r = rA;
        ldsA03[j] = r * 128 + slot * 16;
        srcA03[j] = Xb + (size_t)(tM * 256 + r) * K + ((slot ^ (r & 7)) << 3);
        r = rA + 64;
        ldsA47[j] = r * 128 + slot * 16;
        srcA47[j] = Xb + (size_t)(tM * 256 + r) * K + ((slot ^ (r & 7)) << 3);
        r = rB;
        ldsB01[j] = r * 128 + slot * 16;
        srcB01[j] = Wb + (size_t)(tN * 256 + r) * K + ((slot ^ (r & 7)) << 3);
        r = rB + 32;
        ldsB23[j] = r * 128 + slot * 16;
        srcB23[j] = Wb + (size_t)(tN * 256 + r) * K + ((slot ^ (r & 7)) << 3);
    }

    f32x4 acc[8][4];
    #pragma unroll
    for (int i = 0; i < 8; ++i)
        #pragma unroll
        for (int j = 0; j < 4; ++j)
            acc[i][j] = (f32x4){0.f, 0.f, 0.f, 0.f};

    // prologue: stage tile0 -> buf0, tile1 -> buf1; wait tile0; preload b01(t0)
    STAGE_R(srcA03, ldsA03, 0, 0);     STAGE_R(srcA47, ldsA47, 0, 0);
    STAGE_R(srcB01, ldsB01, 65536, 0); STAGE_R(srcB23, ldsB23, 65536, 0);
    STAGE_R(srcA03, ldsA03, 32768, 1); STAGE_R(srcA47, ldsA47, 32768, 1);
    STAGE_R(srcB01, ldsB01, 98304, 1); STAGE_R(srcB23, ldsB23, 98304, 1);
    asm volatile("s_waitcnt vmcnt(8)" ::: "memory");
    __builtin_amdgcn_s_barrier();

    bf16x8 a[4][2], b23[2][2], b01[2][2];
    #pragma unroll
    for (int nf = 0; nf < 2; ++nf) {
        b01[nf][0] = *(const bf16x8*)(smem + 65536 + bRow + nf * 2048 + xs0);
        b01[nf][1] = *(const bf16x8*)(smem + 65536 + bRow + nf * 2048 + xs1);
    }

    for (int tt = 0; tt < NT; ++tt) {
        int pA = (tt & 1) * 32768;
        int pB = 65536 + (tt & 1) * 32768;
        int pBn = 65536 + ((~tt) & 1) * 32768;
        bool pre = (tt + 2 < NT);

        // ---- P1: read a03 (8) + b23 (4, for P2/P4); stage B01(tt+2);
        //          MFMA (m03, n01) with b01; b23 floats through (lgkm(4))
        #pragma unroll
        for (int mf = 0; mf < 4; ++mf) {
            a[mf][0] = *(const bf16x8*)(smem + pA + aRow + mf * 2048 + xs0);
            a[mf][1] = *(const bf16x8*)(smem + pA + aRow + mf * 2048 + xs1);
        }
        #pragma unroll
        for (int nf = 0; nf < 2; ++nf) {
            b23[nf][0] = *(const bf16x8*)(smem + pB + bRow + (nf + 2) * 2048 + xs0);
            b23[nf][1] = *(const bf16x8*)(smem + pB + bRow + (nf + 2) * 2048 + xs1);
        }
        if (pre) { STAGE_R(srcB01, ldsB01, pB, tt + 2); }
        asm volatile("s_waitcnt lgkmcnt(8)" ::: "memory");   // 16 outstanding
        __builtin_amdgcn_s_barrier();
        asm volatile("s_waitcnt lgkmcnt(4)");                // b01+a03 done, b23 floats
        __builtin_amdgcn_s_setprio(1);
        #pragma unroll
        for (int mf = 0; mf < 4; ++mf)
            #pragma unroll
            for (int nf = 0; nf < 2; ++nf) {
                MFMA(acc[mf][nf], a[mf][0], b01[nf][0]);
                MFMA(acc[mf][nf], a[mf][1], b01[nf][1]);
            }
        __builtin_amdgcn_s_setprio(0);
        __builtin_amdgcn_s_barrier();

        // ---- P2: no reads; stage A03(tt+2); MFMA (m03, n23) with b23
        if (pre) { STAGE_R(srcA03, ldsA03, pA, tt + 2); }
        __builtin_amdgcn_s_barrier();
        asm volatile("s_waitcnt lgkmcnt(0)");                // instant (b23 landed)
        __builtin_amdgcn_s_setprio(1);
        #pragma unroll
        for (int mf = 0; mf < 4; ++mf)
            #pragma unroll
            for (int nf = 0; nf < 2; ++nf) {
                MFMA(acc[mf][nf + 2], a[mf][0], b23[nf][0]);
                MFMA(acc[mf][nf + 2], a[mf][1], b23[nf][1]);
            }
        __builtin_amdgcn_s_setprio(0);
        __builtin_amdgcn_s_barrier();

        // ---- P3: read a47 (8); stage B23(tt+2); MFMA (m47, n01) with b01
        #pragma unroll
        for (int mf = 0; mf < 4; ++mf) {
            a[mf][0] = *(const bf16x8*)(smem + pA + aRow + (mf + 4) * 2048 + xs0);
            a[mf][1] = *(const bf16x8*)(smem + pA + aRow + (mf + 4) * 2048 + xs1);
        }
        if (pre) { STAGE_R(srcB23, ldsB23, pB, tt + 2); }
        asm volatile("s_waitcnt lgkmcnt(4)" ::: "memory");
        __builtin_amdgcn_s_barrier();
        asm volatile("s_waitcnt lgkmcnt(0)");
        __builtin_amdgcn_s_setprio(1);
        #pragma unroll
        for (int mf = 0; mf < 4; ++mf)
            #pragma unroll
            for (int nf = 0; nf < 2; ++nf) {
                MFMA(acc[mf + 4][nf], a[mf][0], b01[nf][0]);
                MFMA(acc[mf + 4][nf], a[mf][1], b01[nf][1]);
            }
        __builtin_amdgcn_s_setprio(0);
        __builtin_amdgcn_s_barrier();

        // ---- P4: stage A47(tt+2); vmcnt; barrier; preload b01(tt+1) (no wait);
        //          MFMA (m47, n23) with b23
        if (pre) { STAGE_R(srcA47, ldsA47, pA, tt + 2); }
        if (tt < NT - 2) { asm volatile("s_waitcnt vmcnt(8)" ::: "memory"); }
        else             { asm volatile("s_waitcnt vmcnt(0)" ::: "memory"); }
        __builtin_amdgcn_s_barrier();
        if (tt + 1 < NT) {
            #pragma unroll
            for (int nf = 0; nf < 2; ++nf) {
                b01[nf][0] = *(const bf16x8*)(smem + pBn + bRow + nf * 2048 + xs0);
                b01[nf][1] = *(const bf16x8*)(smem + pBn + bRow + nf * 2048 + xs1);
            }
        }
        __builtin_amdgcn_s_setprio(1);
        #pragma unroll
        for (int mf = 0; mf < 4; ++mf)
            #pragma unroll
            for (int nf = 0; nf < 2; ++nf) {
                MFMA(acc[mf + 4][nf + 2], a[mf][0], b23[nf][0]);
                MFMA(acc[mf + 4][nf + 2], a[mf][1], b23[nf][1]);
            }
        __builtin_amdgcn_s_setprio(0);
        __builtin_amdgcn_s_barrier();
    }

    // epilogue: C/D layout col=lane&15, row=(lane>>4)*4+reg
    #pragma unroll
    for (int nf = 0; nf < 4; ++nf) {
        int gn = tN * 256 + wn * 64 + nf * 16 + lr;
        float bs = bias[gn];
        #pragma unroll
        for (int mf = 0; mf < 8; ++mf) {
            #pragma unroll
            for (int r = 0; r < 4; ++r) {
                int gm = tM * 256 + wm * 128 + mf * 16 + hi * 4 + r;
                out[(size_t)gm * N + gn] = acc[mf][nf][r] + bs;
            }
        }
    }
}

extern "C" void kernel_launch(void* const* d_in, const int* in_sizes, int n_in,
                              void* d_out, int out_size, void* d_ws, size_t ws_size,
                              hipStream_t stream) {
    (void)in_sizes; (void)n_in; (void)out_size; (void)ws_size;
    const float* x      = (const float*)d_in[0];
    const int*   qw     = (const int*)d_in[1];
    const float* wmin   = (const float*)d_in[2];
    const float* wscale = (const float*)d_in[3];
    const float* bias   = (const float*)d_in[4];
    const float* A      = (const float*)d_in[5];
    const float* Bm     = (const float*)d_in[6];
    float* out = (float*)d_out;

    u16* Wb = (u16*)d_ws;                         // 4096*4096*2 = 33.5 MB
    u16* Xb = Wb + (size_t)D_OUT * D_IN;          // 8192*4096*2 = 67.1 MB

    dequant_fold_kernel<<<D_OUT / OPB, 256, 0, stream>>>(qw, wmin, wscale, A, Bm, Wb);
    xcast_kernel<<<(M_TOT * D_IN) / (256 * 8), 256, 0, stream>>>(x, Xb);
    gemm_bt_kernel<<<(M_TOT / BM) * (D_OUT / BN), 512, 131072, stream>>>(Xb, Wb, bias, out);
}

// Round 10
// 285.739 us; speedup vs baseline: 1.1529x; 1.0203x over previous
//
#include <hip/hip_runtime.h>
#include <hip/hip_bf16.h>

typedef unsigned short u16;
typedef unsigned int u32;
typedef __bf16 bf16x8 __attribute__((ext_vector_type(8)));
typedef float f32x4 __attribute__((ext_vector_type(4)));
typedef int i32x4 __attribute__((ext_vector_type(4)));
typedef u16 u16x4 __attribute__((ext_vector_type(4)));
typedef u16 u16x8 __attribute__((ext_vector_type(8)));

#define D_IN 4096
#define D_OUT 4096
#define M_TOT 8192
#define RANK_ 16

#define BM 256
#define BN 256
#define BK 64
#define NT (D_IN / BK)   // 64 K-tiles
#define OPB 2            // dequant rows per block

__device__ __forceinline__ u16 f2bf(float f) {
    union { float f; u32 u; } v; v.f = f;
    u32 u = v.u;
    u32 r = (u + 0x7FFFu + ((u >> 16) & 1u)) >> 16;  // round-to-nearest-even
    return (u16)r;
}

// W_eff[o,i] = q[o,i]*scale[o] + min[o] + 2*sum_r B[o,r]*A[r,i]  -> bf16
__global__ __launch_bounds__(256) void dequant_fold_kernel(
        const int* __restrict__ q, const float* __restrict__ wmin,
        const float* __restrict__ wscale, const float* __restrict__ A,
        const float* __restrict__ Bm, u16* __restrict__ Wb) {
    const int K = D_IN;
    int o0 = blockIdx.x * OPB;
    float s0 = wscale[o0], s1 = wscale[o0 + 1];
    float m0 = wmin[o0],   m1 = wmin[o0 + 1];
    float Br0[RANK_], Br1[RANK_];   // block-uniform -> SGPRs
    #pragma unroll
    for (int r = 0; r < RANK_; ++r) {
        Br0[r] = 2.0f * Bm[(size_t)o0 * RANK_ + r];
        Br1[r] = 2.0f * Bm[(size_t)(o0 + 1) * RANK_ + r];
    }
    for (int i4 = threadIdx.x; i4 < K / 4; i4 += 256) {
        int i = i4 * 4;
        i32x4 q0 = __builtin_nontemporal_load((const i32x4*)(q + (size_t)o0 * K + i));
        i32x4 q1 = __builtin_nontemporal_load((const i32x4*)(q + (size_t)(o0 + 1) * K + i));
        float v00 = (float)q0.x * s0 + m0, v01 = (float)q0.y * s0 + m0;
        float v02 = (float)q0.z * s0 + m0, v03 = (float)q0.w * s0 + m0;
        float v10 = (float)q1.x * s1 + m1, v11 = (float)q1.y * s1 + m1;
        float v12 = (float)q1.z * s1 + m1, v13 = (float)q1.w * s1 + m1;
        #pragma unroll
        for (int r = 0; r < RANK_; ++r) {
            f32x4 av = *(const f32x4*)(A + (size_t)r * K + i);
            v00 += Br0[r] * av.x; v01 += Br0[r] * av.y;
            v02 += Br0[r] * av.z; v03 += Br0[r] * av.w;
            v10 += Br1[r] * av.x; v11 += Br1[r] * av.y;
            v12 += Br1[r] * av.z; v13 += Br1[r] * av.w;
        }
        u16x4 o0v, o1v;
        o0v.x = f2bf(v00); o0v.y = f2bf(v01); o0v.z = f2bf(v02); o0v.w = f2bf(v03);
        o1v.x = f2bf(v10); o1v.y = f2bf(v11); o1v.z = f2bf(v12); o1v.w = f2bf(v13);
        *(u16x4*)(Wb + (size_t)o0 * K + i) = o0v;
        *(u16x4*)(Wb + (size_t)(o0 + 1) * K + i) = o1v;
    }
}

// fp32 -> bf16, 8 elems/thread; x is single-pass -> non-temporal load
__global__ void xcast_kernel(const float* __restrict__ x, u16* __restrict__ xb) {
    size_t i = (size_t)blockIdx.x * blockDim.x + threadIdx.x;
    const f32x4* p = (const f32x4*)x + i * 2;
    f32x4 a = __builtin_nontemporal_load(p);
    f32x4 b = __builtin_nontemporal_load(p + 1);
    u16x8 o;
    o[0] = f2bf(a.x); o[1] = f2bf(a.y); o[2] = f2bf(a.z); o[3] = f2bf(a.w);
    o[4] = f2bf(b.x); o[5] = f2bf(b.y); o[6] = f2bf(b.z); o[7] = f2bf(b.w);
    *(u16x8*)(xb + i * 8) = o;
}

// ---- 256x256 8-phase GEMM, fully rotated reads (shadow-issue) ----
// Quadrant order (m03,n01)(m03,n23)(m47,n01)(m47,n23).
// ALL ds_reads issue in an earlier phase's shadow, zero extra registers:
//   b01(tt+1): P4 pre-MFMA (after vmcnt+barrier; b01 dead after P3)
//   a03(tt+1)+b23(tt+1): P4 post-MFMA (a,b23 dead after P4's MFMA)
//   a47(tt):  P2 post-MFMA (a dead after P2's MFMA; region landed P4(tt-1))
// Pre-MFMA waits: P1 lgkm(4) [FIFO b01,a03,b23 -> b23 floats], P2 lgkm(0)
// [b23 landed under P1 MFMA], P3 lgkm(0) [a47 landed under P2-close], P4 none.
// Staging 2 loads/phase: P1 B01(tt+2), P2 A03, P3 B23, P4 A47;
// vmcnt(8) once per tile (8 newest = tile tt+2 stay in flight).

#define STAGE_R(sarr, larr, base, kt) do { _Pragma("unroll") \
    for (int j_ = 0; j_ < 2; ++j_) \
        __builtin_amdgcn_global_load_lds( \
            (__attribute__((address_space(1))) u32*)(sarr[j_] + (kt) * 64), \
            (__attribute__((address_space(3))) u32*)(smem + (base) + larr[j_]), \
            16, 0, 0); } while (0)

#define MFMA(d, va, vb) d = __builtin_amdgcn_mfma_f32_16x16x32_bf16(va, vb, d, 0, 0, 0)

__global__ __launch_bounds__(512, 2) void gemm_bt_kernel(const u16* __restrict__ Xb,
                                                         const u16* __restrict__ Wb,
                                                         const float* __restrict__ bias,
                                                         float* __restrict__ out) {
    extern __shared__ __align__(16) char smem[];   // 131072 B
    const int K = D_IN, N = D_OUT;

    int bid = blockIdx.x;                  // 512 blocks
    int swz = (bid & 7) * 64 + (bid >> 3); // XCD swizzle, bijective (512 % 8 == 0)
    int tM = swz >> 4;                     // 32 M-tiles
    int tN = swz & 15;                     // 16 N-tiles

    int t = threadIdx.x;
    int lane = t & 63;
    int wave = t >> 6;
    int wm = wave >> 2;                    // 0..1
    int wn = wave & 3;                     // 0..3
    int lr = lane & 15;
    int hi = lane >> 4;
    int l7 = lane & 7;

    // ds_read byte offsets: row*128 + swizzled 16B slot (slot ^= row&7).
    int xs0 = ((0 * 4 + hi) ^ l7) << 4;    // ks=0
    int xs1 = ((1 * 4 + hi) ^ l7) << 4;    // ks=1
    int aRow = (wm * 128 + lr) * 128;      // + mf*2048
    int bRow = (wn * 64 + lr) * 128;       // + nf*2048

    // Staging: 4 regions x 2 rounds; thread t handles chunk j*512+t of each.
    // Regions (rows): A03={0-63,128-191} A47=+64  B01={0-31,64-95,128-159,192-223} B23=+32
    // LDS dest linear (row*128+slot*16); global source slot pre-XORed (rule 21).
    const u16 *srcA03[2], *srcA47[2], *srcB01[2], *srcB23[2];
    int ldsA03[2], ldsA47[2], ldsB01[2], ldsB23[2];
    #pragma unroll
    for (int j = 0; j < 2; ++j) {
        int idx = j * 512 + t;
        int rl = idx >> 3, slot = idx & 7;
        int rA = (rl & 63) + ((rl >> 6) << 7);
        int rB = (rl & 31) + ((rl >> 5) << 6);
        int r = rA;
        ldsA03[j] = r * 128 + slot * 16;
        srcA03[j] = Xb + (size_t)(tM * 256 + r) * K + ((slot ^ (r & 7)) << 3);
        r = rA + 64;
        ldsA47[j] = r * 128 + slot * 16;
        srcA47[j] = Xb + (size_t)(tM * 256 + r) * K + ((slot ^ (r & 7)) << 3);
        r = rB;
        ldsB01[j] = r * 128 + slot * 16;
        srcB01[j] = Wb + (size_t)(tN * 256 + r) * K + ((slot ^ (r & 7)) << 3);
        r = rB + 32;
        ldsB23[j] = r * 128 + slot * 16;
        srcB23[j] = Wb + (size_t)(tN * 256 + r) * K + ((slot ^ (r & 7)) << 3);
    }

    f32x4 acc[8][4];
    #pragma unroll
    for (int i = 0; i < 8; ++i)
        #pragma unroll
        for (int j = 0; j < 4; ++j)
            acc[i][j] = (f32x4){0.f, 0.f, 0.f, 0.f};

    // prologue: stage tile0 -> buf0, tile1 -> buf1; wait tile0;
    // pre-read b01(t0), a03(t0), b23(t0) (the "P4-tail" of a virtual tt=-1)
    STAGE_R(srcA03, ldsA03, 0, 0);     STAGE_R(srcA47, ldsA47, 0, 0);
    STAGE_R(srcB01, ldsB01, 65536, 0); STAGE_R(srcB23, ldsB23, 65536, 0);
    STAGE_R(srcA03, ldsA03, 32768, 1); STAGE_R(srcA47, ldsA47, 32768, 1);
    STAGE_R(srcB01, ldsB01, 98304, 1); STAGE_R(srcB23, ldsB23, 98304, 1);
    asm volatile("s_waitcnt vmcnt(8)" ::: "memory");
    __builtin_amdgcn_s_barrier();

    bf16x8 a[4][2], b23[2][2], b01[2][2];
    #pragma unroll
    for (int nf = 0; nf < 2; ++nf) {
        b01[nf][0] = *(const bf16x8*)(smem + 65536 + bRow + nf * 2048 + xs0);
        b01[nf][1] = *(const bf16x8*)(smem + 65536 + bRow + nf * 2048 + xs1);
    }
    #pragma unroll
    for (int mf = 0; mf < 4; ++mf) {
        a[mf][0] = *(const bf16x8*)(smem + aRow + mf * 2048 + xs0);
        a[mf][1] = *(const bf16x8*)(smem + aRow + mf * 2048 + xs1);
    }
    #pragma unroll
    for (int nf = 0; nf < 2; ++nf) {
        b23[nf][0] = *(const bf16x8*)(smem + 65536 + bRow + (nf + 2) * 2048 + xs0);
        b23[nf][1] = *(const bf16x8*)(smem + 65536 + bRow + (nf + 2) * 2048 + xs1);
    }

    for (int tt = 0; tt < NT; ++tt) {
        int pA = (tt & 1) * 32768;
        int pB = 65536 + (tt & 1) * 32768;
        int pBn = 65536 + ((~tt) & 1) * 32768;
        int pAn = ((~tt) & 1) * 32768;
        bool pre = (tt + 2 < NT);

        // ---- P1: no reads; stage B01(tt+2); MFMA (m03, n01)
        //      lgkm(4): FIFO [b01(4), a03(8), b23(4)] -> b01+a03 done, b23 floats
        if (pre) { STAGE_R(srcB01, ldsB01, pB, tt + 2); }
        __builtin_amdgcn_s_barrier();
        asm volatile("s_waitcnt lgkmcnt(4)");
        __builtin_amdgcn_s_setprio(1);
        #pragma unroll
        for (int mf = 0; mf < 4; ++mf)
            #pragma unroll
            for (int nf = 0; nf < 2; ++nf) {
                MFMA(acc[mf][nf], a[mf][0], b01[nf][0]);
                MFMA(acc[mf][nf], a[mf][1], b01[nf][1]);
            }
        __builtin_amdgcn_s_setprio(0);
        __builtin_amdgcn_s_barrier();

        // ---- P2: stage A03(tt+2); MFMA (m03, n23); post-MFMA read a47(tt)
        if (pre) { STAGE_R(srcA03, ldsA03, pA, tt + 2); }
        __builtin_amdgcn_s_barrier();
        asm volatile("s_waitcnt lgkmcnt(0)");                // b23 landed under P1
        __builtin_amdgcn_s_setprio(1);
        #pragma unroll
        for (int mf = 0; mf < 4; ++mf)
            #pragma unroll
            for (int nf = 0; nf < 2; ++nf) {
                MFMA(acc[mf][nf + 2], a[mf][0], b23[nf][0]);
                MFMA(acc[mf][nf + 2], a[mf][1], b23[nf][1]);
            }
        __builtin_amdgcn_s_setprio(0);
        #pragma unroll
        for (int mf = 0; mf < 4; ++mf) {                     // a-regs dead -> a47
            a[mf][0] = *(const bf16x8*)(smem + pA + aRow + (mf + 4) * 2048 + xs0);
            a[mf][1] = *(const bf16x8*)(smem + pA + aRow + (mf + 4) * 2048 + xs1);
        }
        __builtin_amdgcn_s_barrier();

        // ---- P3: stage B23(tt+2); MFMA (m47, n01) with b01
        if (pre) { STAGE_R(srcB23, ldsB23, pB, tt + 2); }
        __builtin_amdgcn_s_barrier();
        asm volatile("s_waitcnt lgkmcnt(0)");                // a47 landed under close
        __builtin_amdgcn_s_setprio(1);
        #pragma unroll
        for (int mf = 0; mf < 4; ++mf)
            #pragma unroll
            for (int nf = 0; nf < 2; ++nf) {
                MFMA(acc[mf + 4][nf], a[mf][0], b01[nf][0]);
                MFMA(acc[mf + 4][nf], a[mf][1], b01[nf][1]);
            }
        __builtin_amdgcn_s_setprio(0);
        __builtin_amdgcn_s_barrier();

        // ---- P4: stage A47(tt+2); vmcnt; barrier; pre-MFMA read b01(tt+1);
        //          MFMA (m47, n23); post-MFMA read a03(tt+1)+b23(tt+1)
        if (pre) { STAGE_R(srcA47, ldsA47, pA, tt + 2); }
        if (tt < NT - 2) { asm volatile("s_waitcnt vmcnt(8)" ::: "memory"); }
        else             { asm volatile("s_waitcnt vmcnt(0)" ::: "memory"); }
        __builtin_amdgcn_s_barrier();
        if (tt + 1 < NT) {
            #pragma unroll
            for (int nf = 0; nf < 2; ++nf) {                 // b01 dead after P3
                b01[nf][0] = *(const bf16x8*)(smem + pBn + bRow + nf * 2048 + xs0);
                b01[nf][1] = *(const bf16x8*)(smem + pBn + bRow + nf * 2048 + xs1);
            }
        }
        __builtin_amdgcn_s_setprio(1);
        #pragma unroll
        for (int mf = 0; mf < 4; ++mf)
            #pragma unroll
            for (int nf = 0; nf < 2; ++nf) {
                MFMA(acc[mf + 4][nf + 2], a[mf][0], b23[nf][0]);
                MFMA(acc[mf + 4][nf + 2], a[mf][1], b23[nf][1]);
            }
        __builtin_amdgcn_s_setprio(0);
        if (tt + 1 < NT) {
            #pragma unroll
            for (int mf = 0; mf < 4; ++mf) {                 // a-regs dead -> a03(next)
                a[mf][0] = *(const bf16x8*)(smem + pAn + aRow + mf * 2048 + xs0);
                a[mf][1] = *(const bf16x8*)(smem + pAn + aRow + mf * 2048 + xs1);
            }
            #pragma unroll
            for (int nf = 0; nf < 2; ++nf) {                 // b23 dead -> b23(next)
                b23[nf][0] = *(const bf16x8*)(smem + pBn + bRow + (nf + 2) * 2048 + xs0);
                b23[nf][1] = *(const bf16x8*)(smem + pBn + bRow + (nf + 2) * 2048 + xs1);
            }
        }
        __builtin_amdgcn_s_barrier();
    }

    // epilogue: C/D layout col=lane&15, row=(lane>>4)*4+reg
    #pragma unroll
    for (int nf = 0; nf < 4; ++nf) {
        int gn = tN * 256 + wn * 64 + nf * 16 + lr;
        float bs = bias[gn];
        #pragma unroll
        for (int mf = 0; mf < 8; ++mf) {
            #pragma unroll
            for (int r = 0; r < 4; ++r) {
                int gm = tM * 256 + wm * 128 + mf * 16 + hi * 4 + r;
                out[(size_t)gm * N + gn] = acc[mf][nf][r] + bs;
            }
        }
    }
}

extern "C" void kernel_launch(void* const* d_in, const int* in_sizes, int n_in,
                              void* d_out, int out_size, void* d_ws, size_t ws_size,
                              hipStream_t stream) {
    (void)in_sizes; (void)n_in; (void)out_size; (void)ws_size;
    const float* x      = (const float*)d_in[0];
    const int*   qw     = (const int*)d_in[1];
    const float* wmin   = (const float*)d_in[2];
    const float* wscale = (const float*)d_in[3];
    const float* bias   = (const float*)d_in[4];
    const float* A      = (const float*)d_in[5];
    const float* Bm     = (const float*)d_in[6];
    float* out = (float*)d_out;

    u16* Wb = (u16*)d_ws;                         // 4096*4096*2 = 33.5 MB
    u16* Xb = Wb + (size_t)D_OUT * D_IN;          // 8192*4096*2 = 67.1 MB

    dequant_fold_kernel<<<D_OUT / OPB, 256, 0, stream>>>(qw, wmin, wscale, A, Bm, Wb);
    xcast_kernel<<<(M_TOT * D_IN) / (256 * 8), 256, 0, stream>>>(x, Xb);
    gemm_bt_kernel<<<(M_TOT / BM) * (D_OUT / BN), 512, 131072, stream>>>(Xb, Wb, bias, out);
}